// Round 2
// baseline (669.682 us; speedup 1.0000x reference)
//
#include <hip/hip_runtime.h>
#include <math.h>

// ---------------------------------------------------------------------------
// ADSAGE: 2x SAGEConv (mean aggr) + softmax + GCNConv, fp32.
// edge_index arrives as int32 (harness converts integer inputs to int).
// CSR-by-dst built per launch (histogram + single-block scan + scatter),
// then gather-based aggregations (no fp32 atomics).
// ---------------------------------------------------------------------------

__global__ void zero_kernel(int* __restrict__ p, int n) {
    int i = blockIdx.x * blockDim.x + threadIdx.x;
    if (i < n) p[i] = 0;
}

__global__ void hist_kernel(const int* __restrict__ dst,
                            int* __restrict__ rowptr, int E, int N) {
    int e = blockIdx.x * blockDim.x + threadIdx.x;
    if (e < E) {
        int d = dst[e];
        if ((unsigned)d < (unsigned)N) atomicAdd(&rowptr[d + 1], 1);
    }
}

// In-place inclusive scan over data[0..n-1], single block of 1024 threads.
__global__ void scan_kernel(int* __restrict__ data, int n) {
    __shared__ int sums[1024];
    int t = threadIdx.x;
    int chunk = (n + 1023) / 1024;
    int lo = min(t * chunk, n);
    int hi = min(lo + chunk, n);
    int s = 0;
    for (int i = lo; i < hi; ++i) s += data[i];
    sums[t] = s;
    for (int off = 1; off < 1024; off <<= 1) {
        __syncthreads();
        int u = (t >= off) ? sums[t - off] : 0;
        __syncthreads();
        sums[t] += u;
    }
    __syncthreads();
    int run = (t > 0) ? sums[t - 1] : 0;
    for (int i = lo; i < hi; ++i) {
        run += data[i];
        data[i] = run;
    }
}

__global__ void init_kernel(const int* __restrict__ rowptr, int* __restrict__ cursor,
                            float* __restrict__ dinv, int N) {
    int i = blockIdx.x * blockDim.x + threadIdx.x;
    if (i < N) {
        int s = rowptr[i], e = rowptr[i + 1];
        cursor[i] = s;
        dinv[i] = rsqrtf((float)(e - s + 1));  // GCN degree incl. self loop
    }
}

__global__ void scatter_kernel(const int* __restrict__ src,
                               const int* __restrict__ dst,
                               int* __restrict__ cursor, int* __restrict__ col, int E, int N) {
    int e = blockIdx.x * blockDim.x + threadIdx.x;
    if (e < E) {
        int d = dst[e];
        int sv = src[e];
        if ((unsigned)d < (unsigned)N && (unsigned)sv < (unsigned)N) {
            int pos = atomicAdd(&cursor[d], 1);
            col[pos] = sv;
        }
    }
}

// mean over in-neighbors: out[i][f] = sum_{j in N(i)} x[j][f] / max(deg,1)
template <int F>
__global__ void agg_mean_kernel(const float* __restrict__ x, const int* __restrict__ rowptr,
                                const int* __restrict__ col, float* __restrict__ out, int N) {
    int i = blockIdx.x;
    int f = threadIdx.x;
    int s = rowptr[i], e = rowptr[i + 1];
    float acc = 0.f;
    for (int p = s; p < e; ++p) {
        int j = col[p];
        acc += x[(size_t)j * F + f];
    }
    float c = (float)(e - s);
    out[(size_t)i * F + f] = acc / fmaxf(c, 1.0f);
}

// OUT[N,M] = act(A@Wa (+ B@Wb) + bias), K/M compile-time, 64-row tiles.
template <int K, int M, bool DUAL, bool RELU, bool HASBIAS>
__launch_bounds__(256)
__global__ void gemm_kernel(const float* __restrict__ A, const float* __restrict__ B,
                            const float* __restrict__ Wa, const float* __restrict__ Wb,
                            const float* __restrict__ bias, float* __restrict__ out, int N) {
    constexpr int NBUF = DUAL ? 2 : 1;
    __shared__ float smem[NBUF * 64 * K];
    float* As = smem;
    float* Bs = smem + (DUAL ? 64 * K : 0);

    const int tid = threadIdx.x;
    const int row0 = blockIdx.x * 64;

    constexpr int VPT = (64 * K) / (256 * 4);  // float4 loads per thread
#pragma unroll
    for (int v = 0; v < VPT; ++v) {
        int flat = tid + v * 256;        // float4 units
        int r = flat / (K / 4);
        int c4 = (flat % (K / 4)) * 4;
        int row = row0 + r;
        float4 a = make_float4(0.f, 0.f, 0.f, 0.f);
        float4 b = make_float4(0.f, 0.f, 0.f, 0.f);
        if (row < N) {
            a = *(const float4*)(A + (size_t)row * K + c4);
            if (DUAL) b = *(const float4*)(B + (size_t)row * K + c4);
        }
        *(float4*)(As + r * K + c4) = a;
        if (DUAL) *(float4*)(Bs + r * K + c4) = b;
    }
    __syncthreads();

    const int tx = tid & 63;
    const int ty = tid >> 6;          // 0..3 -> 16-row group
    constexpr int CPT = M / 64;       // cols per thread (1 or 2)

    float acc[16][CPT];
#pragma unroll
    for (int r = 0; r < 16; ++r)
#pragma unroll
        for (int c = 0; c < CPT; ++c) acc[r][c] = 0.f;

#pragma unroll 4
    for (int k4 = 0; k4 < K / 4; ++k4) {
        float wa[4][CPT], wb[4][CPT];
#pragma unroll
        for (int kk = 0; kk < 4; ++kk)
#pragma unroll
            for (int c = 0; c < CPT; ++c) {
                wa[kk][c] = Wa[(size_t)(k4 * 4 + kk) * M + tx + c * 64];
                if (DUAL) wb[kk][c] = Wb[(size_t)(k4 * 4 + kk) * M + tx + c * 64];
            }
#pragma unroll
        for (int r = 0; r < 16; ++r) {
            float4 a = *(const float4*)(As + (ty * 16 + r) * K + k4 * 4);
#pragma unroll
            for (int c = 0; c < CPT; ++c)
                acc[r][c] += a.x * wa[0][c] + a.y * wa[1][c] + a.z * wa[2][c] + a.w * wa[3][c];
            if (DUAL) {
                float4 b = *(const float4*)(Bs + (ty * 16 + r) * K + k4 * 4);
#pragma unroll
                for (int c = 0; c < CPT; ++c)
                    acc[r][c] += b.x * wb[0][c] + b.y * wb[1][c] + b.z * wb[2][c] + b.w * wb[3][c];
            }
        }
    }

#pragma unroll
    for (int r = 0; r < 16; ++r) {
        int row = row0 + ty * 16 + r;
        if (row < N) {
#pragma unroll
            for (int c = 0; c < CPT; ++c) {
                float v = acc[r][c];
                if (HASBIAS) v += bias[tx + c * 64];
                if (RELU) v = fmaxf(v, 0.f);
                out[(size_t)row * M + tx + c * 64] = v;
            }
        }
    }
}

// row softmax over 64 features, one wave per row, in place
__global__ void softmax64_kernel(float* __restrict__ h, int N) {
    int row = blockIdx.x * 4 + (threadIdx.x >> 6);
    int lane = threadIdx.x & 63;
    if (row >= N) return;
    float v = h[(size_t)row * 64 + lane];
    float m = v;
#pragma unroll
    for (int o = 32; o > 0; o >>= 1) m = fmaxf(m, __shfl_xor(m, o, 64));
    float ex = expf(v - m);
    float s = ex;
#pragma unroll
    for (int o = 32; o > 0; o >>= 1) s += __shfl_xor(s, o, 64);
    h[(size_t)row * 64 + lane] = ex / s;
}

// out[i] = dinv[i] * sum_{j in N(i)} xw[j]*dinv[j]  + xw[i]*dinv[i]^2 + bg
__global__ void gcn_agg_kernel(const float* __restrict__ xw, const int* __restrict__ rowptr,
                               const int* __restrict__ col, const float* __restrict__ dinv,
                               const float* __restrict__ bg, float* __restrict__ out, int N) {
    int i = blockIdx.x;
    int f = threadIdx.x;  // 64
    int s = rowptr[i], e = rowptr[i + 1];
    float acc = 0.f;
    for (int p = s; p < e; ++p) {
        int j = col[p];
        acc += xw[(size_t)j * 64 + f] * dinv[j];
    }
    float di = dinv[i];
    out[(size_t)i * 64 + f] = acc * di + xw[(size_t)i * 64 + f] * di * di + bg[f];
}

extern "C" void kernel_launch(void* const* d_in, const int* in_sizes, int n_in,
                              void* d_out, int out_size, void* d_ws, size_t ws_size,
                              hipStream_t stream) {
    const float* x = (const float*)d_in[0];
    const int* ei = (const int*)d_in[1];    // int32 per harness conversion
    const float* W1l = (const float*)d_in[2];
    const float* b1l = (const float*)d_in[3];
    const float* W1r = (const float*)d_in[4];
    const float* W2l = (const float*)d_in[5];
    const float* b2l = (const float*)d_in[6];
    const float* W2r = (const float*)d_in[7];
    const float* Wg  = (const float*)d_in[8];
    const float* bg  = (const float*)d_in[9];

    const int N = in_sizes[0] / 128;
    const int E = in_sizes[1] / 2;
    const int* srcp = ei;
    const int* dstp = ei + E;

    // workspace layout
    float* ws = (float*)d_ws;
    float* agg  = ws;                          // N*128 (also reused as xw)
    float* h1   = agg + (size_t)N * 128;       // N*128
    float* h2   = h1 + (size_t)N * 128;        // N*64
    float* dinv = h2 + (size_t)N * 64;         // N
    int* rowptr = (int*)(dinv + N);            // N+1
    int* cursor = rowptr + (N + 1);            // N
    int* col    = cursor + N;                  // E
    float* xw   = agg;                         // alias (agg dead by then)

    float* out = (float*)d_out;

    zero_kernel<<<(N + 1 + 255) / 256, 256, 0, stream>>>(rowptr, N + 1);
    hist_kernel<<<(E + 255) / 256, 256, 0, stream>>>(dstp, rowptr, E, N);
    scan_kernel<<<1, 1024, 0, stream>>>(rowptr, N + 1);
    init_kernel<<<(N + 255) / 256, 256, 0, stream>>>(rowptr, cursor, dinv, N);
    scatter_kernel<<<(E + 255) / 256, 256, 0, stream>>>(srcp, dstp, cursor, col, E, N);

    // SAGE layer 1: h1 = relu(mean@W1l + b1l + x@W1r)
    agg_mean_kernel<128><<<N, 128, 0, stream>>>(x, rowptr, col, agg, N);
    gemm_kernel<128, 128, true, true, true>
        <<<(N + 63) / 64, 256, 0, stream>>>(agg, x, W1l, W1r, b1l, h1, N);

    // SAGE layer 2: h2 = mean(h1)@W2l + b2l + h1@W2r
    agg_mean_kernel<128><<<N, 128, 0, stream>>>(h1, rowptr, col, agg, N);
    gemm_kernel<128, 64, true, false, true>
        <<<(N + 63) / 64, 256, 0, stream>>>(agg, h1, W2l, W2r, b2l, h2, N);

    // softmax rows
    softmax64_kernel<<<(N + 3) / 4, 256, 0, stream>>>(h2, N);

    // GCN: xw = p @ Wg ; out = norm-aggregate + bg
    gemm_kernel<64, 64, false, false, false>
        <<<(N + 63) / 64, 256, 0, stream>>>(h2, nullptr, Wg, nullptr, nullptr, xw, N);
    gcn_agg_kernel<<<N, 64, 0, stream>>>(xw, rowptr, col, dinv, bg, out, N);
}

// Round 3
// 614.104 us; speedup vs baseline: 1.0905x; 1.0905x over previous
//
#include <hip/hip_runtime.h>
#include <math.h>

// ---------------------------------------------------------------------------
// ADSAGE: 2x SAGEConv (mean aggr) + softmax + GCNConv, fp32.
// Key identity: mean-aggregation is linear => aggregate AFTER the linear
// transform. Pipeline:
//   pq = x @ [W1l | W1r]            (N,256)  GEMM K=128 M=256
//   h1 = relu(gather_mean(p) + q + b1l)      (N,128)  fused gather
//   rs = h1 @ [W2l | W2r]           (N,128)  GEMM K=128 M=128
//   h2 = softmax(gather_mean(r) + s + b2l)   (N,64)   fused gather+softmax
//   t  = h2 @ Wg                    (N,64)   GEMM K=64 M=64
//   out = dinv*(gather(t*dinv)) + t*dinv^2 + bg       fused gather
// ---------------------------------------------------------------------------

__global__ void zero_kernel(int* __restrict__ p, int n) {
    int i = blockIdx.x * blockDim.x + threadIdx.x;
    if (i < n) p[i] = 0;
}

__global__ void hist_kernel(const int* __restrict__ dst,
                            int* __restrict__ rowptr, int E, int N) {
    int e = blockIdx.x * blockDim.x + threadIdx.x;
    if (e < E) {
        int d = dst[e];
        if ((unsigned)d < (unsigned)N) atomicAdd(&rowptr[d + 1], 1);
    }
}

// In-place inclusive scan, single block of 1024 threads.
__global__ void scan_kernel(int* __restrict__ data, int n) {
    __shared__ int sums[1024];
    int t = threadIdx.x;
    int chunk = (n + 1023) / 1024;
    int lo = min(t * chunk, n);
    int hi = min(lo + chunk, n);
    int s = 0;
    for (int i = lo; i < hi; ++i) s += data[i];
    sums[t] = s;
    for (int off = 1; off < 1024; off <<= 1) {
        __syncthreads();
        int u = (t >= off) ? sums[t - off] : 0;
        __syncthreads();
        sums[t] += u;
    }
    __syncthreads();
    int run = (t > 0) ? sums[t - 1] : 0;
    for (int i = lo; i < hi; ++i) {
        run += data[i];
        data[i] = run;
    }
}

__global__ void init_kernel(const int* __restrict__ rowptr, int* __restrict__ cursor,
                            float* __restrict__ dinv, int N) {
    int i = blockIdx.x * blockDim.x + threadIdx.x;
    if (i < N) {
        int s = rowptr[i], e = rowptr[i + 1];
        cursor[i] = s;
        dinv[i] = rsqrtf((float)(e - s + 1));  // GCN degree incl. self loop
    }
}

__global__ void scatter_kernel(const int* __restrict__ src,
                               const int* __restrict__ dst,
                               int* __restrict__ cursor, int* __restrict__ col, int E, int N) {
    int e = blockIdx.x * blockDim.x + threadIdx.x;
    if (e < E) {
        int d = dst[e];
        int sv = src[e];
        if ((unsigned)d < (unsigned)N && (unsigned)sv < (unsigned)N) {
            int pos = atomicAdd(&cursor[d], 1);
            col[pos] = sv;
        }
    }
}

// ---------------------------------------------------------------------------
// GEMM: out[N, M=CPT*64] = A[N,K] @ W.  Lane owns CPT contiguous output cols
// (m0 = tx*CPT) -> weight loads are float{CPT} vectors, output stores
// contiguous.  DUAL: cols [0,M/2) from WA, [M/2,M) from WB (both lead dim ldw).
// 64-row tiles, A staged in LDS (broadcast ds_read_b128 per row).
// ---------------------------------------------------------------------------
template <int K, int CPT, bool DUAL>
__launch_bounds__(256)
__global__ void gemm_kernel(const float* __restrict__ A,
                            const float* __restrict__ WA, const float* __restrict__ WB,
                            int ldw, float* __restrict__ out, int N) {
    constexpr int M = CPT * 64;
    __shared__ float As[64 * K];

    const int tid = threadIdx.x;
    const int row0 = blockIdx.x * 64;

    constexpr int VPT = (64 * K) / (256 * 4);  // float4 loads per thread
#pragma unroll
    for (int v = 0; v < VPT; ++v) {
        int flat = tid + v * 256;
        int r = flat / (K / 4);
        int c4 = (flat % (K / 4)) * 4;
        int row = row0 + r;
        float4 a = make_float4(0.f, 0.f, 0.f, 0.f);
        if (row < N) a = *(const float4*)(A + (size_t)row * K + c4);
        *(float4*)(As + r * K + c4) = a;
    }
    __syncthreads();

    const int tx = tid & 63;
    const int ty = tid >> 6;
    const int m0 = tx * CPT;
    const float* base = (!DUAL || m0 < M / 2) ? (WA + m0) : (WB + (m0 - M / 2));

    float acc[16][CPT];
#pragma unroll
    for (int r = 0; r < 16; ++r)
#pragma unroll
        for (int c = 0; c < CPT; ++c) acc[r][c] = 0.f;

#pragma unroll 4
    for (int k4 = 0; k4 < K / 4; ++k4) {
        float wv[4][CPT];
#pragma unroll
        for (int kk = 0; kk < 4; ++kk) {
            const float* wp = base + (size_t)(k4 * 4 + kk) * ldw;
            if (CPT == 4) {
                float4 w = *(const float4*)wp;
                wv[kk][0] = w.x; wv[kk][1] = w.y; wv[kk][2] = w.z; wv[kk][3] = w.w;
            } else if (CPT == 2) {
                float2 w = *(const float2*)wp;
                wv[kk][0] = w.x; wv[kk][1] = w.y;
            } else {
                wv[kk][0] = *wp;
            }
        }
#pragma unroll
        for (int r = 0; r < 16; ++r) {
            float4 a = *(const float4*)(As + (ty * 16 + r) * K + k4 * 4);
#pragma unroll
            for (int c = 0; c < CPT; ++c)
                acc[r][c] += a.x * wv[0][c] + a.y * wv[1][c] + a.z * wv[2][c] + a.w * wv[3][c];
        }
    }

#pragma unroll
    for (int r = 0; r < 16; ++r) {
        int row = row0 + ty * 16 + r;
        if (row < N) {
            float* op = out + (size_t)row * M + m0;
            if (CPT == 4) {
                float4 st = make_float4(acc[r][0], acc[r][1], acc[r][2], acc[r][3]);
                *(float4*)op = st;
            } else if (CPT == 2) {
                float2 st = make_float2(acc[r][0], acc[r][1]);
                *(float2*)op = st;
            } else {
                *op = acc[r][0];
            }
        }
    }
}

// h1[i] = relu(mean_j pq[j][0:128] + pq[i][128:256] + b1l); wave per node, float2 lanes
__global__ void agg1_relu_kernel(const float* __restrict__ pq, const int* __restrict__ rowptr,
                                 const int* __restrict__ col, const float* __restrict__ b1l,
                                 float* __restrict__ h1, int N) {
    int node = blockIdx.x * 4 + (threadIdx.x >> 6);
    if (node >= N) return;
    int lane = threadIdx.x & 63;
    int s = rowptr[node], e = rowptr[node + 1];
    float ax = 0.f, ay = 0.f;
    for (int p = s; p < e; ++p) {
        int j = col[p];
        float2 v = *(const float2*)(pq + (size_t)j * 256 + lane * 2);
        ax += v.x; ay += v.y;
    }
    float inv = 1.0f / fmaxf((float)(e - s), 1.0f);
    float2 q = *(const float2*)(pq + (size_t)node * 256 + 128 + lane * 2);
    float2 b = *(const float2*)(b1l + lane * 2);
    float2 r;
    r.x = fmaxf(ax * inv + q.x + b.x, 0.f);
    r.y = fmaxf(ay * inv + q.y + b.y, 0.f);
    *(float2*)(h1 + (size_t)node * 128 + lane * 2) = r;
}

// h2[i] = softmax(mean_j rs[j][0:64] + rs[i][64:128] + b2l); wave per node
__global__ void agg2_softmax_kernel(const float* __restrict__ rs, const int* __restrict__ rowptr,
                                    const int* __restrict__ col, const float* __restrict__ b2l,
                                    float* __restrict__ h2, int N) {
    int node = blockIdx.x * 4 + (threadIdx.x >> 6);
    if (node >= N) return;
    int lane = threadIdx.x & 63;
    int s = rowptr[node], e = rowptr[node + 1];
    float acc = 0.f;
    for (int p = s; p < e; ++p) {
        int j = col[p];
        acc += rs[(size_t)j * 128 + lane];
    }
    float inv = 1.0f / fmaxf((float)(e - s), 1.0f);
    float v = acc * inv + rs[(size_t)node * 128 + 64 + lane] + b2l[lane];
    float m = v;
#pragma unroll
    for (int o = 32; o > 0; o >>= 1) m = fmaxf(m, __shfl_xor(m, o, 64));
    float ex = expf(v - m);
    float ssum = ex;
#pragma unroll
    for (int o = 32; o > 0; o >>= 1) ssum += __shfl_xor(ssum, o, 64);
    h2[(size_t)node * 64 + lane] = ex / ssum;
}

// out[i] = dinv[i]*sum_j t[j]*dinv[j] + t[i]*dinv[i]^2 + bg; wave per node
__global__ void gcn_agg_kernel(const float* __restrict__ t, const int* __restrict__ rowptr,
                               const int* __restrict__ col, const float* __restrict__ dinv,
                               const float* __restrict__ bg, float* __restrict__ out, int N) {
    int node = blockIdx.x * 4 + (threadIdx.x >> 6);
    if (node >= N) return;
    int lane = threadIdx.x & 63;
    int s = rowptr[node], e = rowptr[node + 1];
    float acc = 0.f;
    for (int p = s; p < e; ++p) {
        int j = col[p];
        acc += t[(size_t)j * 64 + lane] * dinv[j];
    }
    float di = dinv[node];
    out[(size_t)node * 64 + lane] =
        acc * di + t[(size_t)node * 64 + lane] * di * di + bg[lane];
}

extern "C" void kernel_launch(void* const* d_in, const int* in_sizes, int n_in,
                              void* d_out, int out_size, void* d_ws, size_t ws_size,
                              hipStream_t stream) {
    const float* x = (const float*)d_in[0];
    const int* ei = (const int*)d_in[1];    // int32 per harness conversion
    const float* W1l = (const float*)d_in[2];
    const float* b1l = (const float*)d_in[3];
    const float* W1r = (const float*)d_in[4];
    const float* W2l = (const float*)d_in[5];
    const float* b2l = (const float*)d_in[6];
    const float* W2r = (const float*)d_in[7];
    const float* Wg  = (const float*)d_in[8];
    const float* bg  = (const float*)d_in[9];

    const int N = in_sizes[0] / 128;
    const int E = in_sizes[1] / 2;
    const int* srcp = ei;
    const int* dstp = ei + E;

    // workspace layout (aliasing: pq region reused for rs, h2, t)
    float* ws = (float*)d_ws;
    float* pq   = ws;                          // N*256
    float* h1   = pq + (size_t)N * 256;        // N*128
    float* rs   = pq;                          // N*128 (pq dead after agg1)
    float* h2   = pq + (size_t)N * 128;        // N*64
    float* t    = pq + (size_t)N * 192;        // N*64
    float* dinv = h1 + (size_t)N * 128;        // N
    int* rowptr = (int*)(dinv + N);            // N+1
    int* cursor = rowptr + (N + 1);            // N
    int* col    = cursor + N;                  // E

    float* out = (float*)d_out;

    zero_kernel<<<(N + 1 + 255) / 256, 256, 0, stream>>>(rowptr, N + 1);
    hist_kernel<<<(E + 255) / 256, 256, 0, stream>>>(dstp, rowptr, E, N);
    scan_kernel<<<1, 1024, 0, stream>>>(rowptr, N + 1);
    init_kernel<<<(N + 255) / 256, 256, 0, stream>>>(rowptr, cursor, dinv, N);
    scatter_kernel<<<(E + 255) / 256, 256, 0, stream>>>(srcp, dstp, cursor, col, E, N);

    const int gb = (N + 63) / 64;
    const int ab = (N + 3) / 4;

    // pq = x @ [W1l | W1r]
    gemm_kernel<128, 4, true><<<gb, 256, 0, stream>>>(x, W1l, W1r, 128, pq, N);
    // h1 = relu(mean(p) + q + b1l)
    agg1_relu_kernel<<<ab, 256, 0, stream>>>(pq, rowptr, col, b1l, h1, N);

    // rs = h1 @ [W2l | W2r]
    gemm_kernel<128, 2, true><<<gb, 256, 0, stream>>>(h1, W2l, W2r, 64, rs, N);
    // h2 = softmax(mean(r) + s + b2l)
    agg2_softmax_kernel<<<ab, 256, 0, stream>>>(rs, rowptr, col, b2l, h2, N);

    // t = h2 @ Wg
    gemm_kernel<64, 1, false><<<gb, 256, 0, stream>>>(h2, Wg, nullptr, 64, t, N);
    // out = gcn aggregate + bg
    gcn_agg_kernel<<<ab, 256, 0, stream>>>(t, rowptr, col, dinv, bg, out, N);
}

// Round 4
// 469.861 us; speedup vs baseline: 1.4253x; 1.3070x over previous
//
#include <hip/hip_runtime.h>
#include <math.h>

// ---------------------------------------------------------------------------
// ADSAGE: 2x SAGEConv (mean aggr) + softmax + GCNConv, fp32.
// Aggregate-after-GEMM (mean is linear). GEMMs on matrix cores via
// split-bf16 (3-term): a*w ~= ah*wh + al*wh + ah*wl, fp32 accumulate.
//   pq = x @ [W1l|W1r]  (N,256)   MFMA GEMM K=128
//   h1 = relu(mean(p) + q + b1l)  (N,128)   fused gather
//   rs = h1 @ [W2l|W2r] (N,128)   MFMA GEMM K=128
//   h2 = softmax(mean(r) + s + b2l) (N,64)  fused gather+softmax
//   t  = h2 @ Wg        (N,64)    MFMA GEMM K=64
//   out = dinv*gather(t*dinv) + t*dinv^2 + bg
// ---------------------------------------------------------------------------

typedef __attribute__((ext_vector_type(8))) short bf16x8;
typedef __attribute__((ext_vector_type(4))) float f32x4;

__device__ inline unsigned short f32_bf16_hi(float f) {
    unsigned int u = __builtin_bit_cast(unsigned int, f);
    u = (u + 0x7FFFu + ((u >> 16) & 1u)) >> 16;
    return (unsigned short)u;
}
__device__ inline float bf16_to_f32(unsigned short h) {
    unsigned int u = ((unsigned int)h) << 16;
    return __builtin_bit_cast(float, u);
}

// ------------------------------ CSR build ----------------------------------
__global__ void zero_kernel(int* __restrict__ p, int n) {
    int i = blockIdx.x * blockDim.x + threadIdx.x;
    if (i < n) p[i] = 0;
}

__global__ void hist_kernel(const int* __restrict__ dst,
                            int* __restrict__ rowptr, int E, int N) {
    int e = blockIdx.x * blockDim.x + threadIdx.x;
    if (e < E) {
        int d = dst[e];
        if ((unsigned)d < (unsigned)N) atomicAdd(&rowptr[d + 1], 1);
    }
}

__global__ void scan_kernel(int* __restrict__ data, int n) {
    __shared__ int sums[1024];
    int t = threadIdx.x;
    int chunk = (n + 1023) / 1024;
    int lo = min(t * chunk, n);
    int hi = min(lo + chunk, n);
    int s = 0;
    for (int i = lo; i < hi; ++i) s += data[i];
    sums[t] = s;
    for (int off = 1; off < 1024; off <<= 1) {
        __syncthreads();
        int u = (t >= off) ? sums[t - off] : 0;
        __syncthreads();
        sums[t] += u;
    }
    __syncthreads();
    int run = (t > 0) ? sums[t - 1] : 0;
    for (int i = lo; i < hi; ++i) {
        run += data[i];
        data[i] = run;
    }
}

__global__ void init_kernel(const int* __restrict__ rowptr, int* __restrict__ cursor,
                            float* __restrict__ dinv, int N) {
    int i = blockIdx.x * blockDim.x + threadIdx.x;
    if (i < N) {
        int s = rowptr[i], e = rowptr[i + 1];
        cursor[i] = s;
        dinv[i] = rsqrtf((float)(e - s + 1));
    }
}

__global__ void scatter_kernel(const int* __restrict__ src,
                               const int* __restrict__ dst,
                               int* __restrict__ cursor, int* __restrict__ col, int E, int N) {
    int e = blockIdx.x * blockDim.x + threadIdx.x;
    if (e < E) {
        int d = dst[e];
        int sv = src[e];
        if ((unsigned)d < (unsigned)N && (unsigned)sv < (unsigned)N) {
            int pos = atomicAdd(&cursor[d], 1);
            col[pos] = sv;
        }
    }
}

// -------------------------- weight pre-pack --------------------------------
// Pack W (fp32, row-major [K][Mpart]) into MFMA-B-fragment order, split into
// bf16 hi/lo: element B[k][col] -> frag (s=k/32, t=col/16), lane=(k%32/8)*16
// + col%16, j=k%8; linear pos = ((s*T+t)*64+lane)*8+j.
__global__ void packw_kernel(const float* __restrict__ W1l, const float* __restrict__ W1r,
                             const float* __restrict__ W2l, const float* __restrict__ W2r,
                             const float* __restrict__ Wg,
                             unsigned short* __restrict__ p1h, unsigned short* __restrict__ p1l,
                             unsigned short* __restrict__ p2h, unsigned short* __restrict__ p2l,
                             unsigned short* __restrict__ p3h, unsigned short* __restrict__ p3l) {
    int which = blockIdx.y;
    const float* W;
    unsigned short *hi, *lo;
    int K, Mp, colOff, T;
    if (which == 0)      { W = W1l; hi = p1h; lo = p1l; K = 128; Mp = 128; colOff = 0;   T = 16; }
    else if (which == 1) { W = W1r; hi = p1h; lo = p1l; K = 128; Mp = 128; colOff = 128; T = 16; }
    else if (which == 2) { W = W2l; hi = p2h; lo = p2l; K = 128; Mp = 64;  colOff = 0;   T = 8;  }
    else if (which == 3) { W = W2r; hi = p2h; lo = p2l; K = 128; Mp = 64;  colOff = 64;  T = 8;  }
    else                 { W = Wg;  hi = p3h; lo = p3l; K = 64;  Mp = 64;  colOff = 0;   T = 4;  }
    int idx = blockIdx.x * blockDim.x + threadIdx.x;
    if (idx >= K * Mp) return;
    int k = idx / Mp, m = idx % Mp;
    float w = W[(size_t)k * Mp + m];
    int col = colOff + m;
    int s = k >> 5, kk = k & 31, q = kk >> 3, j = kk & 7;
    int t = col >> 4, n = col & 15;
    int lane = q * 16 + n;
    size_t pos = ((size_t)(s * T + t) * 64 + lane) * 8 + j;
    unsigned short h = f32_bf16_hi(w);
    hi[pos] = h;
    lo[pos] = f32_bf16_hi(w - bf16_to_f32(h));
}

// --------------------------- MFMA GEMM -------------------------------------
// out[N, M] = A[N, K] @ Wpacked. Block = 4 waves, 64 rows; wave owns 16 rows
// x M cols. A converted fp32->bf16 hi/lo in-register. No LDS.
template <int K, int M>
__launch_bounds__(256)
__global__ void gemm_mfma_kernel(const float* __restrict__ A,
                                 const unsigned short* __restrict__ Whi,
                                 const unsigned short* __restrict__ Wlo,
                                 float* __restrict__ out, int N) {
    constexpr int S = K / 32, T = M / 16;
    const int lane = threadIdx.x & 63;
    const int wave = threadIdx.x >> 6;
    const int m = lane & 15, q = lane >> 4;
    const int row0 = blockIdx.x * 64 + wave * 16;
    int arow = row0 + m;
    if (arow >= N) arow = N - 1;       // clamp: only pollutes rows we don't store
    const float* ap = A + (size_t)arow * K + q * 8;

    f32x4 acc[T];
#pragma unroll
    for (int t = 0; t < T; ++t) acc[t] = (f32x4)(0.f);

#pragma unroll
    for (int s = 0; s < S; ++s) {
        float av[8];
        *(float4*)(av)     = *(const float4*)(ap + s * 32);
        *(float4*)(av + 4) = *(const float4*)(ap + s * 32 + 4);
        bf16x8 ahi, alo;
#pragma unroll
        for (int i = 0; i < 8; ++i) {
            unsigned short h = f32_bf16_hi(av[i]);
            ahi[i] = (short)h;
            alo[i] = (short)f32_bf16_hi(av[i] - bf16_to_f32(h));
        }
        const int base = s * T * 64 + lane;
        const bf16x8* whp = (const bf16x8*)Whi;
        const bf16x8* wlp = (const bf16x8*)Wlo;
#pragma unroll
        for (int t = 0; t < T; ++t) {
            bf16x8 wh = whp[base + t * 64];
            bf16x8 wl = wlp[base + t * 64];
            acc[t] = __builtin_amdgcn_mfma_f32_16x16x32_bf16(ahi, wh, acc[t], 0, 0, 0);
            acc[t] = __builtin_amdgcn_mfma_f32_16x16x32_bf16(alo, wh, acc[t], 0, 0, 0);
            acc[t] = __builtin_amdgcn_mfma_f32_16x16x32_bf16(ahi, wl, acc[t], 0, 0, 0);
        }
    }

    // C/D layout: col = lane&15 (=m), row = q*4 + r
#pragma unroll
    for (int r = 0; r < 4; ++r) {
        int row = row0 + q * 4 + r;
        if (row < N) {
            float* op = out + (size_t)row * M + m;
#pragma unroll
            for (int t = 0; t < T; ++t) op[t * 16] = acc[t][r];
        }
    }
}

// ------------------------------ gathers ------------------------------------
// h1[i] = relu(mean_j pq[j][0:128] + pq[i][128:256] + b1l); wave/node, float2
__global__ void agg1_relu_kernel(const float* __restrict__ pq, const int* __restrict__ rowptr,
                                 const int* __restrict__ col, const float* __restrict__ b1l,
                                 float* __restrict__ h1, int N) {
    int node = blockIdx.x * 4 + (threadIdx.x >> 6);
    if (node >= N) return;
    int lane = threadIdx.x & 63;
    int s = rowptr[node], e = rowptr[node + 1];
    float ax = 0.f, ay = 0.f, cx = 0.f, cy = 0.f;
    int p = s;
    for (; p + 2 <= e; p += 2) {
        int j0 = col[p], j1 = col[p + 1];
        float2 v0 = *(const float2*)(pq + (size_t)j0 * 256 + lane * 2);
        float2 v1 = *(const float2*)(pq + (size_t)j1 * 256 + lane * 2);
        ax += v0.x; ay += v0.y; cx += v1.x; cy += v1.y;
    }
    if (p < e) {
        int j0 = col[p];
        float2 v0 = *(const float2*)(pq + (size_t)j0 * 256 + lane * 2);
        ax += v0.x; ay += v0.y;
    }
    ax += cx; ay += cy;
    float inv = 1.0f / fmaxf((float)(e - s), 1.0f);
    float2 qv = *(const float2*)(pq + (size_t)node * 256 + 128 + lane * 2);
    float2 b = *(const float2*)(b1l + lane * 2);
    float2 r;
    r.x = fmaxf(ax * inv + qv.x + b.x, 0.f);
    r.y = fmaxf(ay * inv + qv.y + b.y, 0.f);
    *(float2*)(h1 + (size_t)node * 128 + lane * 2) = r;
}

// h2[i] = softmax(mean_j rs[j][0:64] + rs[i][64:128] + b2l); wave/node
__global__ void agg2_softmax_kernel(const float* __restrict__ rs, const int* __restrict__ rowptr,
                                    const int* __restrict__ col, const float* __restrict__ b2l,
                                    float* __restrict__ h2, int N) {
    int node = blockIdx.x * 4 + (threadIdx.x >> 6);
    if (node >= N) return;
    int lane = threadIdx.x & 63;
    int s = rowptr[node], e = rowptr[node + 1];
    float a0 = 0.f, a1 = 0.f, a2 = 0.f, a3 = 0.f;
    int p = s;
    for (; p + 4 <= e; p += 4) {
        int j0 = col[p], j1 = col[p + 1], j2 = col[p + 2], j3 = col[p + 3];
        a0 += rs[(size_t)j0 * 128 + lane];
        a1 += rs[(size_t)j1 * 128 + lane];
        a2 += rs[(size_t)j2 * 128 + lane];
        a3 += rs[(size_t)j3 * 128 + lane];
    }
    for (; p < e; ++p) a0 += rs[(size_t)col[p] * 128 + lane];
    float acc = (a0 + a1) + (a2 + a3);
    float inv = 1.0f / fmaxf((float)(e - s), 1.0f);
    float v = acc * inv + rs[(size_t)node * 128 + 64 + lane] + b2l[lane];
    float mx = v;
#pragma unroll
    for (int o = 32; o > 0; o >>= 1) mx = fmaxf(mx, __shfl_xor(mx, o, 64));
    float ex = expf(v - mx);
    float ssum = ex;
#pragma unroll
    for (int o = 32; o > 0; o >>= 1) ssum += __shfl_xor(ssum, o, 64);
    h2[(size_t)node * 64 + lane] = ex / ssum;
}

// out[i] = dinv[i]*sum_j t[j]*dinv[j] + t[i]*dinv[i]^2 + bg; wave/node
__global__ void gcn_agg_kernel(const float* __restrict__ t, const int* __restrict__ rowptr,
                               const int* __restrict__ col, const float* __restrict__ dinv,
                               const float* __restrict__ bg, float* __restrict__ out, int N) {
    int node = blockIdx.x * 4 + (threadIdx.x >> 6);
    if (node >= N) return;
    int lane = threadIdx.x & 63;
    int s = rowptr[node], e = rowptr[node + 1];
    float a0 = 0.f, a1 = 0.f;
    int p = s;
    for (; p + 2 <= e; p += 2) {
        int j0 = col[p], j1 = col[p + 1];
        a0 += t[(size_t)j0 * 64 + lane] * dinv[j0];
        a1 += t[(size_t)j1 * 64 + lane] * dinv[j1];
    }
    if (p < e) {
        int j0 = col[p];
        a0 += t[(size_t)j0 * 64 + lane] * dinv[j0];
    }
    float acc = a0 + a1;
    float di = dinv[node];
    out[(size_t)node * 64 + lane] =
        acc * di + t[(size_t)node * 64 + lane] * di * di + bg[lane];
}

extern "C" void kernel_launch(void* const* d_in, const int* in_sizes, int n_in,
                              void* d_out, int out_size, void* d_ws, size_t ws_size,
                              hipStream_t stream) {
    const float* x = (const float*)d_in[0];
    const int* ei = (const int*)d_in[1];    // int32 per harness conversion
    const float* W1l = (const float*)d_in[2];
    const float* b1l = (const float*)d_in[3];
    const float* W1r = (const float*)d_in[4];
    const float* W2l = (const float*)d_in[5];
    const float* b2l = (const float*)d_in[6];
    const float* W2r = (const float*)d_in[7];
    const float* Wg  = (const float*)d_in[8];
    const float* bg  = (const float*)d_in[9];

    const int N = in_sizes[0] / 128;
    const int E = in_sizes[1] / 2;
    const int* srcp = ei;
    const int* dstp = ei + E;

    // workspace layout
    float* ws = (float*)d_ws;
    float* pq   = ws;                          // N*256 (also rs / h2 / t)
    float* h1   = pq + (size_t)N * 256;        // N*128
    float* dinv = h1 + (size_t)N * 128;        // N
    int* rowptr = (int*)(dinv + N);            // N+1
    int* cursor = rowptr + (N + 1);            // N
    int* col    = cursor + N;                  // E
    uintptr_t up = (uintptr_t)(col + E);
    up = (up + 15) & ~(uintptr_t)15;
    unsigned short* p1h = (unsigned short*)up; // 32768 (128x256)
    unsigned short* p1l = p1h + 32768;
    unsigned short* p2h = p1l + 32768;         // 16384 (128x128)
    unsigned short* p2l = p2h + 16384;
    unsigned short* p3h = p2l + 16384;         // 4096 (64x64)
    unsigned short* p3l = p3h + 4096;

    float* rs = pq;                            // N*128 (pq dead after agg1)
    float* h2 = pq + (size_t)N * 128;          // N*64
    float* t  = pq + (size_t)N * 192;          // N*64

    float* out = (float*)d_out;

    zero_kernel<<<(N + 1 + 255) / 256, 256, 0, stream>>>(rowptr, N + 1);
    hist_kernel<<<(E + 255) / 256, 256, 0, stream>>>(dstp, rowptr, E, N);
    scan_kernel<<<1, 1024, 0, stream>>>(rowptr, N + 1);
    init_kernel<<<(N + 255) / 256, 256, 0, stream>>>(rowptr, cursor, dinv, N);
    scatter_kernel<<<(E + 255) / 256, 256, 0, stream>>>(srcp, dstp, cursor, col, E, N);

    packw_kernel<<<dim3(64, 5), 256, 0, stream>>>(W1l, W1r, W2l, W2r, Wg,
                                                  p1h, p1l, p2h, p2l, p3h, p3l);

    const int gb = (N + 63) / 64;
    const int ab = (N + 3) / 4;

    gemm_mfma_kernel<128, 256><<<gb, 256, 0, stream>>>(x, p1h, p1l, pq, N);
    agg1_relu_kernel<<<ab, 256, 0, stream>>>(pq, rowptr, col, b1l, h1, N);

    gemm_mfma_kernel<128, 128><<<gb, 256, 0, stream>>>(h1, p2h, p2l, rs, N);
    agg2_softmax_kernel<<<ab, 256, 0, stream>>>(rs, rowptr, col, b2l, h2, N);

    gemm_mfma_kernel<64, 64><<<gb, 256, 0, stream>>>(h2, p3h, p3l, t, N);
    gcn_agg_kernel<<<ab, 256, 0, stream>>>(t, rowptr, col, dinv, bg, out, N);
}

// Round 5
// 384.699 us; speedup vs baseline: 1.7408x; 1.2214x over previous
//
#include <hip/hip_runtime.h>
#include <math.h>

// ---------------------------------------------------------------------------
// ADSAGE: 2x SAGEConv (mean aggr) + softmax + GCNConv, fp32.
// Aggregate-after-GEMM (mean is linear). GEMMs on matrix cores via
// split-bf16 (3-term): a*w ~= ah*wh + al*wh + ah*wl, fp32 accumulate.
//   pq = x @ [W1l|W1r]  (N,256)   MFMA GEMM K=128
//   h1 = relu(mean(p) + q + b1l)  (N,128)   fused gather
//   rs = h1 @ [W2l|W2r] (N,128)   MFMA GEMM K=128
//   h2 = softmax(mean(r) + s + b2l) (N,64)  fused gather+softmax
//   t  = h2 @ Wg        (N,64)    MFMA GEMM K=64
//   out = dinv*gather(t*dinv) + t*dinv^2 + bg
// CSR rowptr built with a 3-phase hierarchical scan (the single-block scan
// was 80 us = #2 dispatch; 1 CU utilized).
// ---------------------------------------------------------------------------

typedef __attribute__((ext_vector_type(8))) short bf16x8;
typedef __attribute__((ext_vector_type(4))) float f32x4;

__device__ inline unsigned short f32_bf16_hi(float f) {
    unsigned int u = __builtin_bit_cast(unsigned int, f);
    u = (u + 0x7FFFu + ((u >> 16) & 1u)) >> 16;
    return (unsigned short)u;
}
__device__ inline float bf16_to_f32(unsigned short h) {
    unsigned int u = ((unsigned int)h) << 16;
    return __builtin_bit_cast(float, u);
}

// ------------------------------ CSR build ----------------------------------
__global__ void zero_kernel(int* __restrict__ p, int n) {
    int i = blockIdx.x * blockDim.x + threadIdx.x;
    if (i < n) p[i] = 0;
}

__global__ void hist_kernel(const int* __restrict__ dst,
                            int* __restrict__ rowptr, int E, int N) {
    int e = blockIdx.x * blockDim.x + threadIdx.x;
    if (e < E) {
        int d = dst[e];
        if ((unsigned)d < (unsigned)N) atomicAdd(&rowptr[d + 1], 1);
    }
}

// --- hierarchical scan: 2048 elems per block, 256 threads x 8 elems ---
__global__ void scan_reduce_kernel(const int* __restrict__ data, int* __restrict__ bsum, int n) {
    __shared__ int red[256];
    int t = threadIdx.x;
    int base = blockIdx.x * 2048 + t * 8;
    int s = 0;
    if (base + 8 <= n) {
        int4 a = *(const int4*)(data + base);
        int4 b = *(const int4*)(data + base + 4);
        s = a.x + a.y + a.z + a.w + b.x + b.y + b.z + b.w;
    } else {
        for (int i = 0; i < 8; ++i)
            if (base + i < n) s += data[base + i];
    }
    red[t] = s;
    __syncthreads();
    for (int off = 128; off > 0; off >>= 1) {
        if (t < off) red[t] += red[t + off];
        __syncthreads();
    }
    if (t == 0) bsum[blockIdx.x] = red[0];
}

__global__ void scan_offsets_kernel(int* __restrict__ bsum, int B) {
    if (threadIdx.x == 0 && blockIdx.x == 0) {
        int run = 0;
        for (int i = 0; i < B; ++i) { int v = bsum[i]; bsum[i] = run; run += v; }
    }
}

__global__ void scan_final_kernel(int* __restrict__ data, const int* __restrict__ bsum, int n) {
    __shared__ int tsum[256];
    int t = threadIdx.x;
    int base = blockIdx.x * 2048 + t * 8;
    int v[8];
    int s = 0;
#pragma unroll
    for (int i = 0; i < 8; ++i) {
        v[i] = (base + i < n) ? data[base + i] : 0;
        s += v[i];
    }
    tsum[t] = s;
    for (int off = 1; off < 256; off <<= 1) {
        __syncthreads();
        int u = (t >= off) ? tsum[t - off] : 0;
        __syncthreads();
        tsum[t] += u;
    }
    __syncthreads();
    int run = bsum[blockIdx.x] + tsum[t] - s;   // exclusive offset for this thread
#pragma unroll
    for (int i = 0; i < 8; ++i) {
        run += v[i];
        if (base + i < n) data[base + i] = run;
    }
}

__global__ void init_kernel(const int* __restrict__ rowptr, int* __restrict__ cursor,
                            float* __restrict__ dinv, int N) {
    int i = blockIdx.x * blockDim.x + threadIdx.x;
    if (i < N) {
        int s = rowptr[i], e = rowptr[i + 1];
        cursor[i] = s;
        dinv[i] = rsqrtf((float)(e - s + 1));
    }
}

__global__ void scatter_kernel(const int* __restrict__ src,
                               const int* __restrict__ dst,
                               int* __restrict__ cursor, int* __restrict__ col, int E, int N) {
    int e = blockIdx.x * blockDim.x + threadIdx.x;
    if (e < E) {
        int d = dst[e];
        int sv = src[e];
        if ((unsigned)d < (unsigned)N && (unsigned)sv < (unsigned)N) {
            int pos = atomicAdd(&cursor[d], 1);
            col[pos] = sv;
        }
    }
}

// -------------------------- weight pre-pack --------------------------------
__global__ void packw_kernel(const float* __restrict__ W1l, const float* __restrict__ W1r,
                             const float* __restrict__ W2l, const float* __restrict__ W2r,
                             const float* __restrict__ Wg,
                             unsigned short* __restrict__ p1h, unsigned short* __restrict__ p1l,
                             unsigned short* __restrict__ p2h, unsigned short* __restrict__ p2l,
                             unsigned short* __restrict__ p3h, unsigned short* __restrict__ p3l) {
    int which = blockIdx.y;
    const float* W;
    unsigned short *hi, *lo;
    int K, Mp, colOff, T;
    if (which == 0)      { W = W1l; hi = p1h; lo = p1l; K = 128; Mp = 128; colOff = 0;   T = 16; }
    else if (which == 1) { W = W1r; hi = p1h; lo = p1l; K = 128; Mp = 128; colOff = 128; T = 16; }
    else if (which == 2) { W = W2l; hi = p2h; lo = p2l; K = 128; Mp = 64;  colOff = 0;   T = 8;  }
    else if (which == 3) { W = W2r; hi = p2h; lo = p2l; K = 128; Mp = 64;  colOff = 64;  T = 8;  }
    else                 { W = Wg;  hi = p3h; lo = p3l; K = 64;  Mp = 64;  colOff = 0;   T = 4;  }
    int idx = blockIdx.x * blockDim.x + threadIdx.x;
    if (idx >= K * Mp) return;
    int k = idx / Mp, m = idx % Mp;
    float w = W[(size_t)k * Mp + m];
    int col = colOff + m;
    int s = k >> 5, kk = k & 31, q = kk >> 3, j = kk & 7;
    int t = col >> 4, n = col & 15;
    int lane = q * 16 + n;
    size_t pos = ((size_t)(s * T + t) * 64 + lane) * 8 + j;
    unsigned short h = f32_bf16_hi(w);
    hi[pos] = h;
    lo[pos] = f32_bf16_hi(w - bf16_to_f32(h));
}

// --------------------------- MFMA GEMM -------------------------------------
template <int K, int M>
__launch_bounds__(256)
__global__ void gemm_mfma_kernel(const float* __restrict__ A,
                                 const unsigned short* __restrict__ Whi,
                                 const unsigned short* __restrict__ Wlo,
                                 float* __restrict__ out, int N) {
    constexpr int S = K / 32, T = M / 16;
    const int lane = threadIdx.x & 63;
    const int wave = threadIdx.x >> 6;
    const int m = lane & 15, q = lane >> 4;
    const int row0 = blockIdx.x * 64 + wave * 16;
    int arow = row0 + m;
    if (arow >= N) arow = N - 1;       // clamp: only pollutes rows we don't store
    const float* ap = A + (size_t)arow * K + q * 8;

    f32x4 acc[T];
#pragma unroll
    for (int t = 0; t < T; ++t) acc[t] = (f32x4)(0.f);

#pragma unroll
    for (int s = 0; s < S; ++s) {
        float av[8];
        *(float4*)(av)     = *(const float4*)(ap + s * 32);
        *(float4*)(av + 4) = *(const float4*)(ap + s * 32 + 4);
        bf16x8 ahi, alo;
#pragma unroll
        for (int i = 0; i < 8; ++i) {
            unsigned short h = f32_bf16_hi(av[i]);
            ahi[i] = (short)h;
            alo[i] = (short)f32_bf16_hi(av[i] - bf16_to_f32(h));
        }
        const int base = s * T * 64 + lane;
        const bf16x8* whp = (const bf16x8*)Whi;
        const bf16x8* wlp = (const bf16x8*)Wlo;
#pragma unroll
        for (int t = 0; t < T; ++t) {
            bf16x8 wh = whp[base + t * 64];
            bf16x8 wl = wlp[base + t * 64];
            acc[t] = __builtin_amdgcn_mfma_f32_16x16x32_bf16(ahi, wh, acc[t], 0, 0, 0);
            acc[t] = __builtin_amdgcn_mfma_f32_16x16x32_bf16(alo, wh, acc[t], 0, 0, 0);
            acc[t] = __builtin_amdgcn_mfma_f32_16x16x32_bf16(ahi, wl, acc[t], 0, 0, 0);
        }
    }

    // C/D layout: col = lane&15 (=m), row = q*4 + r
#pragma unroll
    for (int r = 0; r < 4; ++r) {
        int row = row0 + q * 4 + r;
        if (row < N) {
            float* op = out + (size_t)row * M + m;
#pragma unroll
            for (int t = 0; t < T; ++t) op[t * 16] = acc[t][r];
        }
    }
}

// ------------------------------ gathers ------------------------------------
// h1[i] = relu(mean_j pq[j][0:128] + pq[i][128:256] + b1l); wave/node, float2 x4 unroll
__global__ void agg1_relu_kernel(const float* __restrict__ pq, const int* __restrict__ rowptr,
                                 const int* __restrict__ col, const float* __restrict__ b1l,
                                 float* __restrict__ h1, int N) {
    int node = blockIdx.x * 4 + (threadIdx.x >> 6);
    if (node >= N) return;
    int lane = threadIdx.x & 63;
    int s = rowptr[node], e = rowptr[node + 1];
    float ax = 0.f, ay = 0.f, bx = 0.f, by = 0.f;
    float cx = 0.f, cy = 0.f, dx = 0.f, dy = 0.f;
    int p = s;
    for (; p + 4 <= e; p += 4) {
        int j0 = col[p], j1 = col[p + 1], j2 = col[p + 2], j3 = col[p + 3];
        float2 v0 = *(const float2*)(pq + (size_t)j0 * 256 + lane * 2);
        float2 v1 = *(const float2*)(pq + (size_t)j1 * 256 + lane * 2);
        float2 v2 = *(const float2*)(pq + (size_t)j2 * 256 + lane * 2);
        float2 v3 = *(const float2*)(pq + (size_t)j3 * 256 + lane * 2);
        ax += v0.x; ay += v0.y; bx += v1.x; by += v1.y;
        cx += v2.x; cy += v2.y; dx += v3.x; dy += v3.y;
    }
    for (; p < e; ++p) {
        int j0 = col[p];
        float2 v0 = *(const float2*)(pq + (size_t)j0 * 256 + lane * 2);
        ax += v0.x; ay += v0.y;
    }
    ax = (ax + bx) + (cx + dx);
    ay = (ay + by) + (cy + dy);
    float inv = 1.0f / fmaxf((float)(e - s), 1.0f);
    float2 qv = *(const float2*)(pq + (size_t)node * 256 + 128 + lane * 2);
    float2 b = *(const float2*)(b1l + lane * 2);
    float2 r;
    r.x = fmaxf(ax * inv + qv.x + b.x, 0.f);
    r.y = fmaxf(ay * inv + qv.y + b.y, 0.f);
    *(float2*)(h1 + (size_t)node * 128 + lane * 2) = r;
}

// h2[i] = softmax(mean_j rs[j][0:64] + rs[i][64:128] + b2l); wave/node
__global__ void agg2_softmax_kernel(const float* __restrict__ rs, const int* __restrict__ rowptr,
                                    const int* __restrict__ col, const float* __restrict__ b2l,
                                    float* __restrict__ h2, int N) {
    int node = blockIdx.x * 4 + (threadIdx.x >> 6);
    if (node >= N) return;
    int lane = threadIdx.x & 63;
    int s = rowptr[node], e = rowptr[node + 1];
    float a0 = 0.f, a1 = 0.f, a2 = 0.f, a3 = 0.f;
    int p = s;
    for (; p + 4 <= e; p += 4) {
        int j0 = col[p], j1 = col[p + 1], j2 = col[p + 2], j3 = col[p + 3];
        a0 += rs[(size_t)j0 * 128 + lane];
        a1 += rs[(size_t)j1 * 128 + lane];
        a2 += rs[(size_t)j2 * 128 + lane];
        a3 += rs[(size_t)j3 * 128 + lane];
    }
    for (; p < e; ++p) a0 += rs[(size_t)col[p] * 128 + lane];
    float acc = (a0 + a1) + (a2 + a3);
    float inv = 1.0f / fmaxf((float)(e - s), 1.0f);
    float v = acc * inv + rs[(size_t)node * 128 + 64 + lane] + b2l[lane];
    float mx = v;
#pragma unroll
    for (int o = 32; o > 0; o >>= 1) mx = fmaxf(mx, __shfl_xor(mx, o, 64));
    float ex = expf(v - mx);
    float ssum = ex;
#pragma unroll
    for (int o = 32; o > 0; o >>= 1) ssum += __shfl_xor(ssum, o, 64);
    h2[(size_t)node * 64 + lane] = ex / ssum;
}

// out[i] = dinv[i]*sum_j t[j]*dinv[j] + t[i]*dinv[i]^2 + bg; wave/node, x4 unroll
__global__ void gcn_agg_kernel(const float* __restrict__ t, const int* __restrict__ rowptr,
                               const int* __restrict__ col, const float* __restrict__ dinv,
                               const float* __restrict__ bg, float* __restrict__ out, int N) {
    int node = blockIdx.x * 4 + (threadIdx.x >> 6);
    if (node >= N) return;
    int lane = threadIdx.x & 63;
    int s = rowptr[node], e = rowptr[node + 1];
    float a0 = 0.f, a1 = 0.f, a2 = 0.f, a3 = 0.f;
    int p = s;
    for (; p + 4 <= e; p += 4) {
        int j0 = col[p], j1 = col[p + 1], j2 = col[p + 2], j3 = col[p + 3];
        a0 += t[(size_t)j0 * 64 + lane] * dinv[j0];
        a1 += t[(size_t)j1 * 64 + lane] * dinv[j1];
        a2 += t[(size_t)j2 * 64 + lane] * dinv[j2];
        a3 += t[(size_t)j3 * 64 + lane] * dinv[j3];
    }
    for (; p < e; ++p) {
        int j0 = col[p];
        a0 += t[(size_t)j0 * 64 + lane] * dinv[j0];
    }
    float acc = (a0 + a1) + (a2 + a3);
    float di = dinv[node];
    out[(size_t)node * 64 + lane] =
        acc * di + t[(size_t)node * 64 + lane] * di * di + bg[lane];
}

extern "C" void kernel_launch(void* const* d_in, const int* in_sizes, int n_in,
                              void* d_out, int out_size, void* d_ws, size_t ws_size,
                              hipStream_t stream) {
    const float* x = (const float*)d_in[0];
    const int* ei = (const int*)d_in[1];    // int32 per harness conversion
    const float* W1l = (const float*)d_in[2];
    const float* b1l = (const float*)d_in[3];
    const float* W1r = (const float*)d_in[4];
    const float* W2l = (const float*)d_in[5];
    const float* b2l = (const float*)d_in[6];
    const float* W2r = (const float*)d_in[7];
    const float* Wg  = (const float*)d_in[8];
    const float* bg  = (const float*)d_in[9];

    const int N = in_sizes[0] / 128;
    const int E = in_sizes[1] / 2;
    const int* srcp = ei;
    const int* dstp = ei + E;

    // workspace layout
    float* ws = (float*)d_ws;
    float* pq   = ws;                          // N*256 (also rs / h2 / t)
    float* h1   = pq + (size_t)N * 256;        // N*128
    float* dinv = h1 + (size_t)N * 128;        // N
    int* rowptr = (int*)(dinv + N);            // N+1
    int* cursor = rowptr + (N + 1);            // N
    int* col    = cursor + N;                  // E
    uintptr_t up = (uintptr_t)(col + E);
    up = (up + 15) & ~(uintptr_t)15;
    unsigned short* p1h = (unsigned short*)up; // 32768 (128x256)
    unsigned short* p1l = p1h + 32768;
    unsigned short* p2h = p1l + 32768;         // 16384 (128x128)
    unsigned short* p2l = p2h + 16384;
    unsigned short* p3h = p2l + 16384;         // 4096 (64x64)
    unsigned short* p3l = p3h + 4096;
    int* bsum = (int*)(p3l + 4096);            // scan block sums (<=64)

    float* rs = pq;                            // N*128 (pq dead after agg1)
    float* h2 = pq + (size_t)N * 128;          // N*64
    float* t  = pq + (size_t)N * 192;          // N*64

    float* out = (float*)d_out;

    const int n1 = N + 1;
    const int SB = (n1 + 2047) / 2048;

    zero_kernel<<<(n1 + 255) / 256, 256, 0, stream>>>(rowptr, n1);
    hist_kernel<<<(E + 255) / 256, 256, 0, stream>>>(dstp, rowptr, E, N);
    scan_reduce_kernel<<<SB, 256, 0, stream>>>(rowptr, bsum, n1);
    scan_offsets_kernel<<<1, 64, 0, stream>>>(bsum, SB);
    scan_final_kernel<<<SB, 256, 0, stream>>>(rowptr, bsum, n1);
    init_kernel<<<(N + 255) / 256, 256, 0, stream>>>(rowptr, cursor, dinv, N);
    scatter_kernel<<<(E + 255) / 256, 256, 0, stream>>>(srcp, dstp, cursor, col, E, N);

    packw_kernel<<<dim3(64, 5), 256, 0, stream>>>(W1l, W1r, W2l, W2r, Wg,
                                                  p1h, p1l, p2h, p2l, p3h, p3l);

    const int gb = (N + 63) / 64;
    const int ab = (N + 3) / 4;

    gemm_mfma_kernel<128, 256><<<gb, 256, 0, stream>>>(x, p1h, p1l, pq, N);
    agg1_relu_kernel<<<ab, 256, 0, stream>>>(pq, rowptr, col, b1l, h1, N);

    gemm_mfma_kernel<128, 128><<<gb, 256, 0, stream>>>(h1, p2h, p2l, rs, N);
    agg2_softmax_kernel<<<ab, 256, 0, stream>>>(rs, rowptr, col, b2l, h2, N);

    gemm_mfma_kernel<64, 64><<<gb, 256, 0, stream>>>(h2, p3h, p3l, t, N);
    gcn_agg_kernel<<<ab, 256, 0, stream>>>(t, rowptr, col, dinv, bg, out, N);
}

// Round 6
// 335.105 us; speedup vs baseline: 1.9984x; 1.1480x over previous
//
#include <hip/hip_runtime.h>
#include <math.h>

// ---------------------------------------------------------------------------
// ADSAGE: 2x SAGEConv (mean aggr) + softmax + GCNConv, fp32.
// Aggregate-after-GEMM (mean is linear). GEMMs on matrix cores via
// split-bf16 (3-term). CSR built with a 2-pass radix sort by dst (buckets =
// dst>>8): per-block LDS histograms -> scan -> partition (contiguous
// per-(block,bucket) writes, avoids 64B-line write amplification) ->
// per-bucket LDS counting sort emitting col coalesced + rowptr + dinv.
// Pipeline:
//   p,q = x @ [W1l|W1r]  (split outputs)        MFMA GEMM K=128
//   h1  = relu(mean(p) + q + b1l)               fused gather
//   r,s = h1 @ [W2l|W2r]                        MFMA GEMM K=128
//   h2  = softmax(mean(r) + s + b2l)            fused gather+softmax
//   t   = h2 @ Wg                               MFMA GEMM K=64
//   out = dinv*gather(t*dinv) + t*dinv^2 + bg   fused gather
// ---------------------------------------------------------------------------

typedef __attribute__((ext_vector_type(8))) short bf16x8;
typedef __attribute__((ext_vector_type(4))) float f32x4;

__device__ inline unsigned short f32_bf16_hi(float f) {
    unsigned int u = __builtin_bit_cast(unsigned int, f);
    u = (u + 0x7FFFu + ((u >> 16) & 1u)) >> 16;
    return (unsigned short)u;
}
__device__ inline float bf16_to_f32(unsigned short h) {
    unsigned int u = ((unsigned int)h) << 16;
    return __builtin_bit_cast(float, u);
}

// ----------------------- radix CSR build (by dst) --------------------------
__global__ void count_kernel(const int* __restrict__ dst, int* __restrict__ off,
                             int E, int NB, int BK) {
    __shared__ int hist[256];
    int t = threadIdx.x;
    hist[t] = 0;
    __syncthreads();
    int base = blockIdx.x * 8192;
    for (int i = t; i < 8192; i += 256) {
        int e = base + i;
        if (e < E) atomicAdd(&hist[dst[e] >> 8], 1);
    }
    __syncthreads();
    if (t < BK) off[1 + t * NB + blockIdx.x] = hist[t];
    if (blockIdx.x == 0 && t == 0) off[0] = 0;
}

__global__ void scan_reduce_kernel(const int* __restrict__ data, int* __restrict__ bsum, int n) {
    __shared__ int red[256];
    int t = threadIdx.x;
    int base = blockIdx.x * 2048 + t * 8;
    int s = 0;
    if (base + 8 <= n) {
        int4 a = *(const int4*)(data + base);
        int4 b = *(const int4*)(data + base + 4);
        s = a.x + a.y + a.z + a.w + b.x + b.y + b.z + b.w;
    } else {
        for (int i = 0; i < 8; ++i)
            if (base + i < n) s += data[base + i];
    }
    red[t] = s;
    __syncthreads();
    for (int off = 128; off > 0; off >>= 1) {
        if (t < off) red[t] += red[t + off];
        __syncthreads();
    }
    if (t == 0) bsum[blockIdx.x] = red[0];
}

__global__ void scan_offsets_kernel(int* __restrict__ bsum, int B) {
    if (threadIdx.x == 0 && blockIdx.x == 0) {
        int run = 0;
        for (int i = 0; i < B; ++i) { int v = bsum[i]; bsum[i] = run; run += v; }
    }
}

__global__ void scan_final_kernel(int* __restrict__ data, const int* __restrict__ bsum, int n) {
    __shared__ int tsum[256];
    int t = threadIdx.x;
    int base = blockIdx.x * 2048 + t * 8;
    int v[8];
    int s = 0;
#pragma unroll
    for (int i = 0; i < 8; ++i) {
        v[i] = (base + i < n) ? data[base + i] : 0;
        s += v[i];
    }
    tsum[t] = s;
    for (int off = 1; off < 256; off <<= 1) {
        __syncthreads();
        int u = (t >= off) ? tsum[t - off] : 0;
        __syncthreads();
        tsum[t] += u;
    }
    __syncthreads();
    int run = bsum[blockIdx.x] + tsum[t] - s;
#pragma unroll
    for (int i = 0; i < 8; ++i) {
        run += v[i];
        if (base + i < n) data[base + i] = run;
    }
}

__global__ void partition_kernel(const int* __restrict__ src, const int* __restrict__ dst,
                                 const int* __restrict__ off, unsigned* __restrict__ ebuf,
                                 int E, int NB, int BK) {
    __shared__ int cur[256];
    int t = threadIdx.x;
    if (t < BK) cur[t] = off[t * NB + blockIdx.x];
    __syncthreads();
    int base = blockIdx.x * 8192;
    for (int i = t; i < 8192; i += 256) {
        int e = base + i;
        if (e < E) {
            int d = dst[e];
            int pos = atomicAdd(&cur[d >> 8], 1);
            ebuf[pos] = ((unsigned)src[e] << 8) | (unsigned)(d & 255);
        }
    }
}

__global__ void finalize_kernel(const unsigned* __restrict__ ebuf, const int* __restrict__ off,
                                int* __restrict__ col, int* __restrict__ rowptr,
                                float* __restrict__ dinv, int N, int NB, int E) {
    __shared__ int hist[256], scn[256], cur[256];
    int b = blockIdx.x, t = threadIdx.x;
    int base = off[b * NB];
    int end  = off[(b + 1) * NB];
    int M = end - base;
    hist[t] = 0;
    __syncthreads();
    for (int i = t; i < M; i += 256) atomicAdd(&hist[ebuf[base + i] & 255u], 1);
    __syncthreads();
    scn[t] = hist[t];
    for (int o = 1; o < 256; o <<= 1) {
        __syncthreads();
        int u = (t >= o) ? scn[t - o] : 0;
        __syncthreads();
        scn[t] += u;
    }
    __syncthreads();
    int excl = scn[t] - hist[t];
    int node = b * 256 + t;
    if (node < N) {
        rowptr[node] = base + excl;
        dinv[node] = rsqrtf((float)(hist[t] + 1));
    }
    if (b == 0 && t == 0) rowptr[N] = E;
    cur[t] = base + excl;
    __syncthreads();
    for (int i = t; i < M; i += 256) {
        unsigned w = ebuf[base + i];
        int pos = atomicAdd(&cur[w & 255u], 1);
        col[pos] = (int)(w >> 8);
    }
}

// -------------------------- weight pre-pack --------------------------------
__global__ void packw_kernel(const float* __restrict__ W1l, const float* __restrict__ W1r,
                             const float* __restrict__ W2l, const float* __restrict__ W2r,
                             const float* __restrict__ Wg,
                             unsigned short* __restrict__ p1h, unsigned short* __restrict__ p1l,
                             unsigned short* __restrict__ p2h, unsigned short* __restrict__ p2l,
                             unsigned short* __restrict__ p3h, unsigned short* __restrict__ p3l) {
    int which = blockIdx.y;
    const float* W;
    unsigned short *hi, *lo;
    int K, Mp, colOff, T;
    if (which == 0)      { W = W1l; hi = p1h; lo = p1l; K = 128; Mp = 128; colOff = 0;   T = 16; }
    else if (which == 1) { W = W1r; hi = p1h; lo = p1l; K = 128; Mp = 128; colOff = 128; T = 16; }
    else if (which == 2) { W = W2l; hi = p2h; lo = p2l; K = 128; Mp = 64;  colOff = 0;   T = 8;  }
    else if (which == 3) { W = W2r; hi = p2h; lo = p2l; K = 128; Mp = 64;  colOff = 64;  T = 8;  }
    else                 { W = Wg;  hi = p3h; lo = p3l; K = 64;  Mp = 64;  colOff = 0;   T = 4;  }
    int idx = blockIdx.x * blockDim.x + threadIdx.x;
    if (idx >= K * Mp) return;
    int k = idx / Mp, m = idx % Mp;
    float w = W[(size_t)k * Mp + m];
    int colI = colOff + m;
    int s = k >> 5, kk = k & 31, qq = kk >> 3, j = kk & 7;
    int tt = colI >> 4, n = colI & 15;
    int lane = qq * 16 + n;
    size_t pos = ((size_t)(s * T + tt) * 64 + lane) * 8 + j;
    unsigned short h = f32_bf16_hi(w);
    hi[pos] = h;
    lo[pos] = f32_bf16_hi(w - bf16_to_f32(h));
}

// --------------------------- MFMA GEMM -------------------------------------
template <int K, int M, bool SPLIT>
__launch_bounds__(256)
__global__ void gemm_mfma_kernel(const float* __restrict__ A,
                                 const unsigned short* __restrict__ Whi,
                                 const unsigned short* __restrict__ Wlo,
                                 float* __restrict__ outA, float* __restrict__ outB, int N) {
    constexpr int S = K / 32, T = M / 16, H = M / 2;
    const int lane = threadIdx.x & 63;
    const int wave = threadIdx.x >> 6;
    const int m = lane & 15, q = lane >> 4;
    const int row0 = blockIdx.x * 64 + wave * 16;
    int arow = row0 + m;
    if (arow >= N) arow = N - 1;       // clamp: only pollutes rows we don't store
    const float* ap = A + (size_t)arow * K + q * 8;

    f32x4 acc[T];
#pragma unroll
    for (int t = 0; t < T; ++t) acc[t] = (f32x4)(0.f);

#pragma unroll
    for (int s = 0; s < S; ++s) {
        float av[8];
        *(float4*)(av)     = *(const float4*)(ap + s * 32);
        *(float4*)(av + 4) = *(const float4*)(ap + s * 32 + 4);
        bf16x8 ahi, alo;
#pragma unroll
        for (int i = 0; i < 8; ++i) {
            unsigned short h = f32_bf16_hi(av[i]);
            ahi[i] = (short)h;
            alo[i] = (short)f32_bf16_hi(av[i] - bf16_to_f32(h));
        }
        const int base = s * T * 64 + lane;
        const bf16x8* whp = (const bf16x8*)Whi;
        const bf16x8* wlp = (const bf16x8*)Wlo;
#pragma unroll
        for (int t = 0; t < T; ++t) {
            bf16x8 wh = whp[base + t * 64];
            bf16x8 wl = wlp[base + t * 64];
            acc[t] = __builtin_amdgcn_mfma_f32_16x16x32_bf16(ahi, wh, acc[t], 0, 0, 0);
            acc[t] = __builtin_amdgcn_mfma_f32_16x16x32_bf16(alo, wh, acc[t], 0, 0, 0);
            acc[t] = __builtin_amdgcn_mfma_f32_16x16x32_bf16(ahi, wl, acc[t], 0, 0, 0);
        }
    }

#pragma unroll
    for (int r = 0; r < 4; ++r) {
        int row = row0 + q * 4 + r;
        if (row < N) {
#pragma unroll
            for (int t = 0; t < T; ++t) {
                int c = t * 16 + m;
                if (!SPLIT) {
                    outA[(size_t)row * M + c] = acc[t][r];
                } else if (c < H) {
                    outA[(size_t)row * H + c] = acc[t][r];
                } else {
                    outB[(size_t)row * H + (c - H)] = acc[t][r];
                }
            }
        }
    }
}

// ------------------------------ gathers ------------------------------------
__global__ void agg1_relu_kernel(const float* __restrict__ p, const float* __restrict__ q,
                                 const int* __restrict__ rowptr, const int* __restrict__ col,
                                 const float* __restrict__ b1l,
                                 float* __restrict__ h1, int N) {
    int node = blockIdx.x * 4 + (threadIdx.x >> 6);
    if (node >= N) return;
    int lane = threadIdx.x & 63;
    int s = rowptr[node], e = rowptr[node + 1];
    float ax = 0.f, ay = 0.f, bx = 0.f, by = 0.f;
    float cx = 0.f, cy = 0.f, dx = 0.f, dy = 0.f;
    int pp = s;
    for (; pp + 4 <= e; pp += 4) {
        int j0 = col[pp], j1 = col[pp + 1], j2 = col[pp + 2], j3 = col[pp + 3];
        float2 v0 = *(const float2*)(p + (size_t)j0 * 128 + lane * 2);
        float2 v1 = *(const float2*)(p + (size_t)j1 * 128 + lane * 2);
        float2 v2 = *(const float2*)(p + (size_t)j2 * 128 + lane * 2);
        float2 v3 = *(const float2*)(p + (size_t)j3 * 128 + lane * 2);
        ax += v0.x; ay += v0.y; bx += v1.x; by += v1.y;
        cx += v2.x; cy += v2.y; dx += v3.x; dy += v3.y;
    }
    for (; pp < e; ++pp) {
        int j0 = col[pp];
        float2 v0 = *(const float2*)(p + (size_t)j0 * 128 + lane * 2);
        ax += v0.x; ay += v0.y;
    }
    ax = (ax + bx) + (cx + dx);
    ay = (ay + by) + (cy + dy);
    float inv = 1.0f / fmaxf((float)(e - s), 1.0f);
    float2 qv = *(const float2*)(q + (size_t)node * 128 + lane * 2);
    float2 b = *(const float2*)(b1l + lane * 2);
    float2 r;
    r.x = fmaxf(ax * inv + qv.x + b.x, 0.f);
    r.y = fmaxf(ay * inv + qv.y + b.y, 0.f);
    *(float2*)(h1 + (size_t)node * 128 + lane * 2) = r;
}

__global__ void agg2_softmax_kernel(const float* __restrict__ rr, const float* __restrict__ ss,
                                    const int* __restrict__ rowptr, const int* __restrict__ col,
                                    const float* __restrict__ b2l,
                                    float* __restrict__ h2, int N) {
    int node = blockIdx.x * 4 + (threadIdx.x >> 6);
    if (node >= N) return;
    int lane = threadIdx.x & 63;
    int s = rowptr[node], e = rowptr[node + 1];
    float a0 = 0.f, a1 = 0.f, a2 = 0.f, a3 = 0.f;
    int p = s;
    for (; p + 4 <= e; p += 4) {
        int j0 = col[p], j1 = col[p + 1], j2 = col[p + 2], j3 = col[p + 3];
        a0 += rr[(size_t)j0 * 64 + lane];
        a1 += rr[(size_t)j1 * 64 + lane];
        a2 += rr[(size_t)j2 * 64 + lane];
        a3 += rr[(size_t)j3 * 64 + lane];
    }
    for (; p < e; ++p) a0 += rr[(size_t)col[p] * 64 + lane];
    float acc = (a0 + a1) + (a2 + a3);
    float inv = 1.0f / fmaxf((float)(e - s), 1.0f);
    float v = acc * inv + ss[(size_t)node * 64 + lane] + b2l[lane];
    float mx = v;
#pragma unroll
    for (int o = 32; o > 0; o >>= 1) mx = fmaxf(mx, __shfl_xor(mx, o, 64));
    float ex = expf(v - mx);
    float ssum = ex;
#pragma unroll
    for (int o = 32; o > 0; o >>= 1) ssum += __shfl_xor(ssum, o, 64);
    h2[(size_t)node * 64 + lane] = ex / ssum;
}

__global__ void gcn_agg_kernel(const float* __restrict__ t, const int* __restrict__ rowptr,
                               const int* __restrict__ col, const float* __restrict__ dinv,
                               const float* __restrict__ bg, float* __restrict__ out, int N) {
    int node = blockIdx.x * 4 + (threadIdx.x >> 6);
    if (node >= N) return;
    int lane = threadIdx.x & 63;
    int s = rowptr[node], e = rowptr[node + 1];
    float a0 = 0.f, a1 = 0.f, a2 = 0.f, a3 = 0.f;
    int p = s;
    for (; p + 4 <= e; p += 4) {
        int j0 = col[p], j1 = col[p + 1], j2 = col[p + 2], j3 = col[p + 3];
        a0 += t[(size_t)j0 * 64 + lane] * dinv[j0];
        a1 += t[(size_t)j1 * 64 + lane] * dinv[j1];
        a2 += t[(size_t)j2 * 64 + lane] * dinv[j2];
        a3 += t[(size_t)j3 * 64 + lane] * dinv[j3];
    }
    for (; p < e; ++p) {
        int j0 = col[p];
        a0 += t[(size_t)j0 * 64 + lane] * dinv[j0];
    }
    float acc = (a0 + a1) + (a2 + a3);
    float di = dinv[node];
    out[(size_t)node * 64 + lane] =
        acc * di + t[(size_t)node * 64 + lane] * di * di + bg[lane];
}

extern "C" void kernel_launch(void* const* d_in, const int* in_sizes, int n_in,
                              void* d_out, int out_size, void* d_ws, size_t ws_size,
                              hipStream_t stream) {
    const float* x = (const float*)d_in[0];
    const int* ei = (const int*)d_in[1];    // int32 per harness conversion
    const float* W1l = (const float*)d_in[2];
    const float* b1l = (const float*)d_in[3];
    const float* W1r = (const float*)d_in[4];
    const float* W2l = (const float*)d_in[5];
    const float* b2l = (const float*)d_in[6];
    const float* W2r = (const float*)d_in[7];
    const float* Wg  = (const float*)d_in[8];
    const float* bg  = (const float*)d_in[9];

    const int N = in_sizes[0] / 128;
    const int E = in_sizes[1] / 2;
    const int* srcp = ei;
    const int* dstp = ei + E;

    const int NB = (E + 8191) / 8192;       // partition blocks
    const int BK = (N + 255) >> 8;          // dst buckets
    const int len = BK * NB;

    // workspace layout
    float* ws = (float*)d_ws;
    float* p    = ws;                          // N*128  (alias: r)
    float* q    = p + (size_t)N * 128;         // N*128  (alias: s)
    float* h1   = q + (size_t)N * 128;         // N*128  (alias: h2, t)
    float* dinv = h1 + (size_t)N * 128;        // N
    int* rowptr = (int*)(dinv + N);            // N+1
    int* off    = rowptr + (N + 1);            // len+2
    int* colbuf = off + len + 2;               // E
    unsigned* ebuf = (unsigned*)(colbuf + E);  // E
    int* bsum   = (int*)(ebuf + E);            // 32
    uintptr_t up = (uintptr_t)(bsum + 32);
    up = (up + 15) & ~(uintptr_t)15;
    unsigned short* p1h = (unsigned short*)up; // 32768 (128x256)
    unsigned short* p1l = p1h + 32768;
    unsigned short* p2h = p1l + 32768;         // 16384 (128x128)
    unsigned short* p2l = p2h + 16384;
    unsigned short* p3h = p2l + 16384;         // 4096 (64x64)
    unsigned short* p3l = p3h + 4096;

    float* r  = p;                             // N*64
    float* s  = q;                             // N*64
    float* h2 = h1;                            // N*64
    float* t  = h1 + (size_t)N * 64;           // N*64

    float* out = (float*)d_out;

    // --- CSR build (radix by dst) ---
    count_kernel<<<NB, 256, 0, stream>>>(dstp, off, E, NB, BK);
    const int sn = len + 1;
    const int SBs = (sn + 2047) / 2048;
    scan_reduce_kernel<<<SBs, 256, 0, stream>>>(off, bsum, sn);
    scan_offsets_kernel<<<1, 64, 0, stream>>>(bsum, SBs);
    scan_final_kernel<<<SBs, 256, 0, stream>>>(off, bsum, sn);
    partition_kernel<<<NB, 256, 0, stream>>>(srcp, dstp, off, ebuf, E, NB, BK);
    finalize_kernel<<<BK, 256, 0, stream>>>(ebuf, off, colbuf, rowptr, dinv, N, NB, E);

    packw_kernel<<<dim3(64, 5), 256, 0, stream>>>(W1l, W1r, W2l, W2r, Wg,
                                                  p1h, p1l, p2h, p2l, p3h, p3l);

    const int gb = (N + 63) / 64;
    const int ab = (N + 3) / 4;

    gemm_mfma_kernel<128, 256, true><<<gb, 256, 0, stream>>>(x, p1h, p1l, p, q, N);
    agg1_relu_kernel<<<ab, 256, 0, stream>>>(p, q, rowptr, colbuf, b1l, h1, N);

    gemm_mfma_kernel<128, 128, true><<<gb, 256, 0, stream>>>(h1, p2h, p2l, r, s, N);
    agg2_softmax_kernel<<<ab, 256, 0, stream>>>(r, s, rowptr, colbuf, b2l, h2, N);

    gemm_mfma_kernel<64, 64, false><<<gb, 256, 0, stream>>>(h2, p3h, p3l, t, nullptr, N);
    gcn_agg_kernel<<<ab, 256, 0, stream>>>(t, rowptr, colbuf, dinv, bg, out, N);
}